// Round 18
// baseline (124.063 us; speedup 1.0000x reference)
//
#include <hip/hip_runtime.h>
#include <hip/hip_bf16.h>
#include <stdint.h>

#define SEQ 2048
#define DIM 1024
#define HEADS 16
#define HD 64
#define NEGV (-1e9f)
#define SCALE2 0.18033688011112042f   // 0.125 * log2(e), folded into Q
#define THR2 11.541560327111707f      // 8 * log2(e)

typedef __attribute__((ext_vector_type(8))) short short8;
typedef __attribute__((ext_vector_type(4))) float f32x4;

__device__ __forceinline__ unsigned short f2bf(float f) {
  __hip_bfloat16 h = __float2bfloat16(f);
  union { __hip_bfloat16 h; unsigned short u; } cv;
  cv.h = h;
  return cv.u;
}

__device__ __forceinline__ void async16(const void* g, void* l) {
  __builtin_amdgcn_global_load_lds(
      (const __attribute__((address_space(1))) unsigned int*)g,
      (__attribute__((address_space(3))) unsigned int*)l, 16, 0, 0);
}

// ---------- merged fp32 -> bf16 cast: y=0 -> x, y=1..4 -> weights ----------
__global__ void cast_all_k(const float* __restrict__ x,
                           const float* __restrict__ w0, const float* __restrict__ w1,
                           const float* __restrict__ w2, const float* __restrict__ w3,
                           unsigned short* __restrict__ xo,
                           unsigned short* __restrict__ o0, unsigned short* __restrict__ o1,
                           unsigned short* __restrict__ o2, unsigned short* __restrict__ o3,
                           int nx4, int nw4) {
  const int seg = blockIdx.y;
  const float* in = (seg == 0) ? x : (seg == 1) ? w0 : (seg == 2) ? w1
                   : (seg == 3) ? w2 : w3;
  unsigned short* out = (seg == 0) ? xo : (seg == 1) ? o0 : (seg == 2) ? o1
                       : (seg == 3) ? o2 : o3;
  const int n4 = (seg == 0) ? nx4 : nw4;
  int stride = gridDim.x * blockDim.x;
  for (int i = blockIdx.x * blockDim.x + threadIdx.x; i < n4; i += stride) {
    float4 v = ((const float4*)in)[i];
    ushort4 o;
    o.x = f2bf(v.x); o.y = f2bf(v.y); o.z = f2bf(v.z); o.w = f2bf(v.w);
    ((ushort4*)out)[i] = o;
  }
}

// ---------- GEMM staging: A[128][32] + B[128][32] tiles, 16B/lane ----------
__device__ __forceinline__ void stage_ab(const unsigned short* __restrict__ A,
                                         const unsigned short* __restrict__ B,
                                         int K, int bm0, int bn0, int k0,
                                         unsigned short* As, unsigned short* Bs,
                                         int tid) {
#pragma unroll
  for (int i = 0; i < 2; ++i) {
    int e   = (i * 256 + tid) * 8;
    int row = e >> 5;
    int kk  = e & 31;
    async16(A + (size_t)(bm0 + row) * K + (size_t)(k0 + kk), As + e);
    async16(B + (size_t)(bn0 + row) * K + (size_t)(k0 + kk), Bs + e);
  }
}

// ---------- shared GEMM core: C[128x128] tile, double-buffered staging ----------
__device__ __forceinline__ void gemm_core(const unsigned short* __restrict__ A,
                                          const unsigned short* __restrict__ B,
                                          int K, int bm0, int bn0,
                                          unsigned short (*As)[128 * 32],
                                          unsigned short (*Bs)[128 * 32],
                                          f32x4 acc[4][4]) {
  const int tid  = threadIdx.x;
  const int lane = tid & 63;
  const int w    = tid >> 6;
  const int wr   = w >> 1, wc = w & 1;
  const int lrow = lane & 15, lkg = lane >> 4;

  stage_ab(A, B, K, bm0, bn0, 0, As[0], Bs[0], tid);
  __syncthreads();   // DMA(0) drained

  for (int k0 = 0; k0 < K; k0 += 32) {
    const int cur = (k0 >> 5) & 1;
    if (k0 + 32 < K)
      stage_ab(A, B, K, bm0, bn0, k0 + 32, As[cur ^ 1], Bs[cur ^ 1], tid);

    short8 af[4], bf[4];
#pragma unroll
    for (int i = 0; i < 4; ++i) {
      af[i] = *(const short8*)(As[cur] + (wr * 64 + i * 16 + lrow) * 32 + lkg * 8);
      bf[i] = *(const short8*)(Bs[cur] + (wc * 64 + i * 16 + lrow) * 32 + lkg * 8);
    }
#pragma unroll
    for (int i = 0; i < 4; ++i)
#pragma unroll
      for (int j = 0; j < 4; ++j)
        acc[i][j] = __builtin_amdgcn_mfma_f32_16x16x32_bf16(af[i], bf[j], acc[i][j], 0, 0, 0);

    __syncthreads();   // drains stage(k+1); all waves done reading buf[cur]
  }
}

// ---------- fused QKV projection (Q pre-scaled by SCALE2 for attn) ----------
__global__ __launch_bounds__(256)
void qkv_gemm_k(const unsigned short* __restrict__ xb,
                const unsigned short* __restrict__ wqb,
                const unsigned short* __restrict__ wkb,
                const unsigned short* __restrict__ wvb,
                const float* __restrict__ bq, const float* __restrict__ bk,
                const float* __restrict__ bv,
                unsigned short* __restrict__ Qb, unsigned short* __restrict__ Kb,
                unsigned short* __restrict__ Vtb) {
  __shared__ __align__(16) unsigned short As[2][128 * 32];
  __shared__ __align__(16) unsigned short Bs[2][128 * 32];
  const int z = blockIdx.z;
  const unsigned short* B = (z == 0) ? wqb : (z == 1) ? wkb : wvb;
  const float* bias       = (z == 0) ? bq  : (z == 1) ? bk  : bv;
  const int bm0 = blockIdx.y * 128, bn0 = blockIdx.x * 128;

  f32x4 acc[4][4] = {};
  gemm_core(xb, B, DIM, bm0, bn0, As, Bs, acc);

  const int lane = threadIdx.x & 63;
  const int w = threadIdx.x >> 6, wr = w >> 1, wc = w & 1;
  unsigned short* out01 = (z == 0) ? Qb : Kb;
  const float oscale = (z == 0) ? SCALE2 : 1.0f;
#pragma unroll
  for (int i = 0; i < 4; ++i)
#pragma unroll
    for (int j = 0; j < 4; ++j)
#pragma unroll
      for (int r = 0; r < 4; ++r) {
        int mg = bm0 + wr * 64 + i * 16 + (lane >> 4) * 4 + r;
        int ng = bn0 + wc * 64 + j * 16 + (lane & 15);
        float v = (acc[i][j][r] + bias[ng]) * oscale;
        int bb = mg >> 11, s = mg & 2047, h = ng >> 6, d = ng & 63;
        int bh = bb * HEADS + h;
        if (z < 2)
          out01[((size_t)bh * SEQ + s) * HD + d] = f2bf(v);   // [b,h,s,d]
        else
          Vtb[((size_t)bh * HD + d) * SEQ + s] = f2bf(v);     // [b,h,d,s]
      }
}

// ---------- output projection: 128x64 tile for 2 blocks/CU occupancy ----------
// grid (16, 32): 512 blocks. Wave w owns rows bm0+w*32..+32, cols bn0..+64.
// LDS = 2*(8K A + 4K B) = 24 KB. Same linear layout/staging idiom as 128^2.
__global__ __launch_bounds__(256)
void out_gemm_k(const unsigned short* __restrict__ Ob,
                const unsigned short* __restrict__ wob,
                const float* __restrict__ bo, float* __restrict__ out) {
  __shared__ __align__(16) unsigned short As[2][128 * 32];
  __shared__ __align__(16) unsigned short Bs[2][64 * 32];
  const int tid  = threadIdx.x;
  const int lane = tid & 63;
  const int w    = tid >> 6;             // 0..3 = row strip
  const int lrow = lane & 15, lkg = lane >> 4;
  const int bm0 = blockIdx.y * 128, bn0 = blockIdx.x * 64;
  const int K = DIM;

#define STAGE64(k0, buf)                                                      \
  {                                                                           \
    _Pragma("unroll")                                                         \
    for (int i = 0; i < 2; ++i) {                                             \
      const int c = i * 256 + tid;       /* A: 512 chunks 16B */              \
      const int row = c >> 2, kk = (c & 3) * 8;                               \
      async16(Ob + (size_t)(bm0 + row) * K + (size_t)((k0) + kk),             \
              As[buf] + c * 8);                                               \
    }                                                                         \
    {                                                                         \
      const int c = tid;                 /* B: 256 chunks 16B */              \
      const int row = c >> 2, kk = (c & 3) * 8;                               \
      async16(wob + (size_t)(bn0 + row) * K + (size_t)((k0) + kk),            \
              Bs[buf] + c * 8);                                               \
    }                                                                         \
  }

  f32x4 acc[2][4] = {};
  STAGE64(0, 0);
  __syncthreads();   // DMA(0) drained

  for (int k0 = 0; k0 < K; k0 += 32) {
    const int cur = (k0 >> 5) & 1;
    if (k0 + 32 < K) STAGE64(k0 + 32, cur ^ 1);

    short8 af[2], bf[4];
#pragma unroll
    for (int i = 0; i < 2; ++i)
      af[i] = *(const short8*)(As[cur] + (w * 32 + i * 16 + lrow) * 32 + lkg * 8);
#pragma unroll
    for (int j = 0; j < 4; ++j)
      bf[j] = *(const short8*)(Bs[cur] + (j * 16 + lrow) * 32 + lkg * 8);
#pragma unroll
    for (int i = 0; i < 2; ++i)
#pragma unroll
      for (int j = 0; j < 4; ++j)
        acc[i][j] = __builtin_amdgcn_mfma_f32_16x16x32_bf16(af[i], bf[j], acc[i][j], 0, 0, 0);

    __syncthreads();   // drains stage(k+1); all waves done reading buf[cur]
  }
#undef STAGE64

#pragma unroll
  for (int i = 0; i < 2; ++i)
#pragma unroll
    for (int j = 0; j < 4; ++j)
#pragma unroll
      for (int r = 0; r < 4; ++r) {
        int mg = bm0 + w * 32 + i * 16 + (lane >> 4) * 4 + r;
        int ng = bn0 + j * 16 + (lane & 15);
        out[(size_t)mg * DIM + ng] = acc[i][j][r] + bo[ng];
      }
}

// ---------- attention: KVBLK=64 staging, swizzled source ----------
__device__ __forceinline__ void stage_kv64(const unsigned short* __restrict__ kbase,
                                           const unsigned short* __restrict__ vbase,
                                           int k0, unsigned short* KsB,
                                           unsigned short* VsB, int tid) {
#pragma unroll
  for (int j = 0; j < 2; ++j) {
    const int c    = j * 256 + tid;   // 512 chunks of 16B: K[64][64]
    const int row  = c >> 3;
    const int colb = (c & 7) << 4;
    const int srcb = colb ^ ((row & 7) << 4);
    async16(kbase + (size_t)(k0 + row) * HD + (srcb >> 1), KsB + c * 8);
  }
#pragma unroll
  for (int j = 0; j < 2; ++j) {
    const int c    = j * 256 + tid;   // V[64 d][64 k]
    const int d    = c >> 3;
    const int colb = (c & 7) << 4;
    const int srcb = colb ^ ((d & 7) << 4);
    async16(vbase + (size_t)d * SEQ + k0 + (srcb >> 1), VsB + c * 8);
  }
}

// ---------- flash attention: single-Q block, double-buffered KVBLK=64 ----------
// grid (32 bh, 32 qbpos) x 256 threads. qb = 31-blockIdx.y, x-fastest =>
// globally longest-first (LPT); 1024 blocks at 4/CU give dynamic backfill.
// LDS = 2*8K (K) + 2*8K (V) + 8K (P) = 40960 B. Softmax in exp2 domain with
// Q pre-scaled; shuffle-free common path (defer-max); per-lane partial lsum.
__global__ __launch_bounds__(256)
void attn_k(const unsigned short* __restrict__ Q,
            const unsigned short* __restrict__ Kp,
            const unsigned short* __restrict__ Vt,
            const int* __restrict__ pm,
            unsigned short* __restrict__ O) {
  __shared__ __align__(16) unsigned short Ks[2][64 * 64];
  __shared__ __align__(16) unsigned short Vs[2][64 * 64];
  __shared__ __align__(16) unsigned short plds[4][16 * 64];

  const int tid  = threadIdx.x;
  const int lane = tid & 63;
  const int w    = tid >> 6;
  const int lc = lane & 15, lg = lane >> 4;
  const int qb = 31 - blockIdx.y;          // globally longest-first
  const int bh = blockIdx.x;
  const int b  = bh >> 4, h = bh & 15;

  const size_t base = (size_t)bh * SEQ * HD;
  const unsigned short* kbase = Kp + base;
  const unsigned short* vbase = Vt + (size_t)bh * HD * SEQ;
  const int* pmb = pm + b * SEQ;
  char* pb = (char*)&plds[w][0];
  const int swp = (lc & 7) << 4;

  const int qrow0 = qb * 64 + w * 16;
  const int qrow  = qrow0 + lc;

  short8 qa[2];
  {
    const unsigned short* qp = Q + base + (size_t)qrow * HD + lg * 8;
    qa[0] = *(const short8*)(qp);
    qa[1] = *(const short8*)(qp + 32);
  }

  f32x4 oacc[4] = {};
  float mrow = -1e30f, lsum = 0.f;

  const int nk = qb + 1;                   // 64-wide k-tiles to the diagonal

  stage_kv64(kbase, vbase, 0, Ks[0], Vs[0], tid);

  // per-wave padding-mask scan (overlaps DMA(0); no LDS flag)
  int ok = 1;
  for (int i = lane; i < SEQ / 4; i += 64) {
    int4 v = ((const int4*)pmb)[i];
    ok &= (v.x != 0) & (v.y != 0) & (v.z != 0) & (v.w != 0);
  }
  const bool allones = __all(ok);
  __syncthreads();   // DMA(0) drained

  for (int kt = 0; kt < nk; ++kt) {
    const int cur = kt & 1;
    const int k0 = kt * 64;
    if (kt + 1 < nk)
      stage_kv64(kbase, vbase, k0 + 64, Ks[cur ^ 1], Vs[cur ^ 1], tid);

    // ---- QK^T swapped: mfma(K, Q) -> lane holds S[q=qrow][k-slice];
    //      Q was pre-scaled by 0.125*log2(e) so z is already log2-domain ----
    f32x4 s[4];
    const char* kbuf = (const char*)Ks[cur];
    __builtin_amdgcn_s_setprio(1);
#pragma unroll
    for (int t = 0; t < 4; ++t) {
      const int row = t * 16 + lc;
      const int swk = (row & 7) << 4;
      const char* kr = kbuf + row * 128;
      short8 kb0 = *(const short8*)(kr + ((lg * 16) ^ swk));
      short8 kb1 = *(const short8*)(kr + ((lg * 16 + 64) ^ swk));
      f32x4 z = {};
      z = __builtin_amdgcn_mfma_f32_16x16x32_bf16(kb0, qa[0], z, 0, 0, 0);
      z = __builtin_amdgcn_mfma_f32_16x16x32_bf16(kb1, qa[1], z, 0, 0, 0);
      s[t] = z;
    }
    __builtin_amdgcn_s_setprio(0);

    // ---- masks: full work only if padding has zeros; else diagonal only ----
    if (!allones) {
#pragma unroll
      for (int t = 0; t < 4; ++t) {
        const int kr0 = k0 + t * 16;
        int4 pmv = *(const int4*)(pmb + kr0 + lg * 4);
#pragma unroll
        for (int r = 0; r < 4; ++r) {
          const int kidx = kr0 + lg * 4 + r;
          if (kidx > qrow || (&pmv.x)[r] == 0) s[t][r] = NEGV;
        }
      }
    } else if (kt == qb) {
#pragma unroll
      for (int t = 0; t < 4; ++t)
#pragma unroll
        for (int r = 0; r < 4; ++r) {
          const int kidx = k0 + t * 16 + lg * 4 + r;
          if (kidx > qrow) s[t][r] = NEGV;
        }
    }

    // ---- online softmax: shuffle-free common path (defer-max) ----
    float mx = -1e30f;
#pragma unroll
    for (int t = 0; t < 4; ++t)
      mx = fmaxf(mx, fmaxf(fmaxf(s[t][0], s[t][1]), fmaxf(s[t][2], s[t][3])));
    if (!__all(mx <= mrow + THR2)) {       // rare: true row max + rescale
      mx = fmaxf(mx, __shfl_xor(mx, 16, 64));
      mx = fmaxf(mx, __shfl_xor(mx, 32, 64));
      const float mnew = fmaxf(mrow, mx);
      const float sc = exp2f(mrow - mnew);
      lsum *= sc;
      mrow = mnew;
      const float s0 = __shfl(sc, lg * 4 + 0, 64);
      const float s1 = __shfl(sc, lg * 4 + 1, 64);
      const float s2 = __shfl(sc, lg * 4 + 2, 64);
      const float s3 = __shfl(sc, lg * 4 + 3, 64);
#pragma unroll
      for (int t = 0; t < 4; ++t) {
        oacc[t][0] *= s0; oacc[t][1] *= s1; oacc[t][2] *= s2; oacc[t][3] *= s3;
      }
    }
    // tree-form partial sums: 4 independent accumulators, short dep chain
    float ps[4];
#pragma unroll
    for (int t = 0; t < 4; ++t) {
      const float p0 = exp2f(s[t][0] - mrow);
      const float p1 = exp2f(s[t][1] - mrow);
      const float p2 = exp2f(s[t][2] - mrow);
      const float p3 = exp2f(s[t][3] - mrow);
      s[t][0] = p0; s[t][1] = p1; s[t][2] = p2; s[t][3] = p3;
      ps[t] = (p0 + p1) + (p2 + p3);
    }
    lsum += (ps[0] + ps[1]) + (ps[2] + ps[3]);   // per-lane partial

    // ---- P -> per-wave LDS (bf16, swizzled), wave-synchronous ----
#pragma unroll
    for (int t = 0; t < 4; ++t) {
      short4 pk;
      pk.x = (short)f2bf(s[t][0]); pk.y = (short)f2bf(s[t][1]);
      pk.z = (short)f2bf(s[t][2]); pk.w = (short)f2bf(s[t][3]);
      const int colb = (t * 16 + lg * 4) * 2;
      *(short4*)(pb + lc * 128 + (colb ^ swp)) = pk;
    }
    short8 pa[2];
#pragma unroll
    for (int ks = 0; ks < 2; ++ks)
      pa[ks] = *(const short8*)(pb + lc * 128 + (((ks * 32 + lg * 8) * 2) ^ swp));

    // ---- PV: O += P @ V, V fragments from swizzled LDS ----
    const char* vbuf = (const char*)Vs[cur];
    __builtin_amdgcn_s_setprio(1);
#pragma unroll
    for (int t = 0; t < 4; ++t) {
      const int d = t * 16 + lc;
      const int swv = (d & 7) << 4;
      const char* vr = vbuf + d * 128;
#pragma unroll
      for (int ks = 0; ks < 2; ++ks) {
        short8 vv = *(const short8*)(vr + ((ks * 64 + lg * 16) ^ swv));
        oacc[t] = __builtin_amdgcn_mfma_f32_16x16x32_bf16(pa[ks], vv, oacc[t], 0, 0, 0);
      }
    }
    __builtin_amdgcn_s_setprio(0);

    __syncthreads();   // drains stage(kt+1) DMA; all waves done with buf[cur]
  }

  // ---- epilogue: reduce partial lsum across the 4 row-copies, store ----
  lsum += __shfl_xor(lsum, 16, 64);
  lsum += __shfl_xor(lsum, 32, 64);
  const float l0 = __shfl(lsum, lg * 4 + 0, 64);
  const float l1 = __shfl(lsum, lg * 4 + 1, 64);
  const float l2 = __shfl(lsum, lg * 4 + 2, 64);
  const float l3 = __shfl(lsum, lg * 4 + 3, 64);
  const float i0 = 1.f / l0, i1 = 1.f / l1, i2 = 1.f / l2, i3 = 1.f / l3;
#pragma unroll
  for (int t = 0; t < 4; ++t) {
    const size_t o0 = ((size_t)(b * SEQ + qrow0 + lg * 4)) * DIM + h * HD + t * 16 + lc;
    O[o0]           = f2bf(oacc[t][0] * i0);
    O[o0 + DIM]     = f2bf(oacc[t][1] * i1);
    O[o0 + 2 * DIM] = f2bf(oacc[t][2] * i2);
    O[o0 + 3 * DIM] = f2bf(oacc[t][3] * i3);
  }
}

extern "C" void kernel_launch(void* const* d_in, const int* in_sizes, int n_in,
                              void* d_out, int out_size, void* d_ws, size_t ws_size,
                              hipStream_t stream) {
  const float* x  = (const float*)d_in[0];
  const int*   pm = (const int*)d_in[1];
  const float* Wq = (const float*)d_in[3];
  const float* bq = (const float*)d_in[4];
  const float* Wk = (const float*)d_in[5];
  const float* bk = (const float*)d_in[6];
  const float* Wv = (const float*)d_in[7];
  const float* bv = (const float*)d_in[8];
  const float* Wo = (const float*)d_in[9];
  const float* bo = (const float*)d_in[10];

  const size_t NX = (size_t)4096 * 1024;
  const size_t NW = (size_t)1024 * 1024;

  unsigned short* ws  = (unsigned short*)d_ws;
  unsigned short* xb  = ws;
  unsigned short* wqb = xb + NX;
  unsigned short* wkb = wqb + NW;
  unsigned short* wvb = wkb + NW;
  unsigned short* wob = wvb + NW;
  unsigned short* Qb  = wob + NW;
  unsigned short* Kb  = Qb + NX;
  unsigned short* Vtb = Kb + NX;
  unsigned short* Ob  = xb;   // alias: x no longer needed after QKV GEMM

  cast_all_k<<<dim3(1024, 5), dim3(256), 0, stream>>>(
      x, Wq, Wk, Wv, Wo, xb, wqb, wkb, wvb, wob,
      (int)(NX / 4), (int)(NW / 4));

  qkv_gemm_k<<<dim3(8, 32, 3), dim3(256), 0, stream>>>(xb, wqb, wkb, wvb,
                                                       bq, bk, bv, Qb, Kb, Vtb);

  attn_k<<<dim3(32, 32), dim3(256), 0, stream>>>(Qb, Kb, Vtb, pm, Ob);

  out_gemm_k<<<dim3(16, 32), dim3(256), 0, stream>>>(Ob, wob, bo, (float*)d_out);
}

// Round 19
// 120.736 us; speedup vs baseline: 1.0276x; 1.0276x over previous
//
#include <hip/hip_runtime.h>
#include <hip/hip_bf16.h>
#include <stdint.h>

#define SEQ 2048
#define DIM 1024
#define HEADS 16
#define HD 64
#define NEGV (-1e9f)
#define SCALE2 0.18033688011112042f   // 0.125 * log2(e), folded into Q
#define THR2 11.541560327111707f      // 8 * log2(e)

typedef __attribute__((ext_vector_type(8))) short short8;
typedef __attribute__((ext_vector_type(4))) float f32x4;

__device__ __forceinline__ unsigned short f2bf(float f) {
  __hip_bfloat16 h = __float2bfloat16(f);
  union { __hip_bfloat16 h; unsigned short u; } cv;
  cv.h = h;
  return cv.u;
}

__device__ __forceinline__ void async16(const void* g, void* l) {
  __builtin_amdgcn_global_load_lds(
      (const __attribute__((address_space(1))) unsigned int*)g,
      (__attribute__((address_space(3))) unsigned int*)l, 16, 0, 0);
}

// ---------- merged fp32 -> bf16 cast: y=0 -> x, y=1..4 -> weights ----------
__global__ void cast_all_k(const float* __restrict__ x,
                           const float* __restrict__ w0, const float* __restrict__ w1,
                           const float* __restrict__ w2, const float* __restrict__ w3,
                           unsigned short* __restrict__ xo,
                           unsigned short* __restrict__ o0, unsigned short* __restrict__ o1,
                           unsigned short* __restrict__ o2, unsigned short* __restrict__ o3,
                           int nx4, int nw4) {
  const int seg = blockIdx.y;
  const float* in = (seg == 0) ? x : (seg == 1) ? w0 : (seg == 2) ? w1
                   : (seg == 3) ? w2 : w3;
  unsigned short* out = (seg == 0) ? xo : (seg == 1) ? o0 : (seg == 2) ? o1
                       : (seg == 3) ? o2 : o3;
  const int n4 = (seg == 0) ? nx4 : nw4;
  int stride = gridDim.x * blockDim.x;
  for (int i = blockIdx.x * blockDim.x + threadIdx.x; i < n4; i += stride) {
    float4 v = ((const float4*)in)[i];
    ushort4 o;
    o.x = f2bf(v.x); o.y = f2bf(v.y); o.z = f2bf(v.z); o.w = f2bf(v.w);
    ((ushort4*)out)[i] = o;
  }
}

// ---------- GEMM staging: A[128][32] + B[128][32] tiles, 16B/lane ----------
__device__ __forceinline__ void stage_ab(const unsigned short* __restrict__ A,
                                         const unsigned short* __restrict__ B,
                                         int K, int bm0, int bn0, int k0,
                                         unsigned short* As, unsigned short* Bs,
                                         int tid) {
#pragma unroll
  for (int i = 0; i < 2; ++i) {
    int e   = (i * 256 + tid) * 8;
    int row = e >> 5;
    int kk  = e & 31;
    async16(A + (size_t)(bm0 + row) * K + (size_t)(k0 + kk), As + e);
    async16(B + (size_t)(bn0 + row) * K + (size_t)(k0 + kk), Bs + e);
  }
}

// ---------- shared GEMM core: C[128x128] tile, double-buffered staging ----------
__device__ __forceinline__ void gemm_core(const unsigned short* __restrict__ A,
                                          const unsigned short* __restrict__ B,
                                          int K, int bm0, int bn0,
                                          unsigned short (*As)[128 * 32],
                                          unsigned short (*Bs)[128 * 32],
                                          f32x4 acc[4][4]) {
  const int tid  = threadIdx.x;
  const int lane = tid & 63;
  const int w    = tid >> 6;
  const int wr   = w >> 1, wc = w & 1;
  const int lrow = lane & 15, lkg = lane >> 4;

  stage_ab(A, B, K, bm0, bn0, 0, As[0], Bs[0], tid);
  __syncthreads();   // DMA(0) drained

  for (int k0 = 0; k0 < K; k0 += 32) {
    const int cur = (k0 >> 5) & 1;
    if (k0 + 32 < K)
      stage_ab(A, B, K, bm0, bn0, k0 + 32, As[cur ^ 1], Bs[cur ^ 1], tid);

    short8 af[4], bf[4];
#pragma unroll
    for (int i = 0; i < 4; ++i) {
      af[i] = *(const short8*)(As[cur] + (wr * 64 + i * 16 + lrow) * 32 + lkg * 8);
      bf[i] = *(const short8*)(Bs[cur] + (wc * 64 + i * 16 + lrow) * 32 + lkg * 8);
    }
#pragma unroll
    for (int i = 0; i < 4; ++i)
#pragma unroll
      for (int j = 0; j < 4; ++j)
        acc[i][j] = __builtin_amdgcn_mfma_f32_16x16x32_bf16(af[i], bf[j], acc[i][j], 0, 0, 0);

    __syncthreads();   // drains stage(k+1); all waves done reading buf[cur]
  }
}

// ---------- fused QKV projection (Q pre-scaled by SCALE2 for attn) ----------
__global__ __launch_bounds__(256)
void qkv_gemm_k(const unsigned short* __restrict__ xb,
                const unsigned short* __restrict__ wqb,
                const unsigned short* __restrict__ wkb,
                const unsigned short* __restrict__ wvb,
                const float* __restrict__ bq, const float* __restrict__ bk,
                const float* __restrict__ bv,
                unsigned short* __restrict__ Qb, unsigned short* __restrict__ Kb,
                unsigned short* __restrict__ Vtb) {
  __shared__ __align__(16) unsigned short As[2][128 * 32];
  __shared__ __align__(16) unsigned short Bs[2][128 * 32];
  const int z = blockIdx.z;
  const unsigned short* B = (z == 0) ? wqb : (z == 1) ? wkb : wvb;
  const float* bias       = (z == 0) ? bq  : (z == 1) ? bk  : bv;
  const int bm0 = blockIdx.y * 128, bn0 = blockIdx.x * 128;

  f32x4 acc[4][4] = {};
  gemm_core(xb, B, DIM, bm0, bn0, As, Bs, acc);

  const int lane = threadIdx.x & 63;
  const int w = threadIdx.x >> 6, wr = w >> 1, wc = w & 1;
  unsigned short* out01 = (z == 0) ? Qb : Kb;
  const float oscale = (z == 0) ? SCALE2 : 1.0f;
#pragma unroll
  for (int i = 0; i < 4; ++i)
#pragma unroll
    for (int j = 0; j < 4; ++j)
#pragma unroll
      for (int r = 0; r < 4; ++r) {
        int mg = bm0 + wr * 64 + i * 16 + (lane >> 4) * 4 + r;
        int ng = bn0 + wc * 64 + j * 16 + (lane & 15);
        float v = (acc[i][j][r] + bias[ng]) * oscale;
        int bb = mg >> 11, s = mg & 2047, h = ng >> 6, d = ng & 63;
        int bh = bb * HEADS + h;
        if (z < 2)
          out01[((size_t)bh * SEQ + s) * HD + d] = f2bf(v);   // [b,h,s,d]
        else
          Vtb[((size_t)bh * HD + d) * SEQ + s] = f2bf(v);     // [b,h,d,s]
      }
}

// ---------- output projection (fp32 out + bias) ----------
__global__ __launch_bounds__(256)
void out_gemm_k(const unsigned short* __restrict__ Ob,
                const unsigned short* __restrict__ wob,
                const float* __restrict__ bo, float* __restrict__ out) {
  __shared__ __align__(16) unsigned short As[2][128 * 32];
  __shared__ __align__(16) unsigned short Bs[2][128 * 32];
  const int bm0 = blockIdx.y * 128, bn0 = blockIdx.x * 128;

  f32x4 acc[4][4] = {};
  gemm_core(Ob, wob, DIM, bm0, bn0, As, Bs, acc);

  const int lane = threadIdx.x & 63;
  const int w = threadIdx.x >> 6, wr = w >> 1, wc = w & 1;
#pragma unroll
  for (int i = 0; i < 4; ++i)
#pragma unroll
    for (int j = 0; j < 4; ++j)
#pragma unroll
      for (int r = 0; r < 4; ++r) {
        int mg = bm0 + wr * 64 + i * 16 + (lane >> 4) * 4 + r;
        int ng = bn0 + wc * 64 + j * 16 + (lane & 15);
        out[(size_t)mg * DIM + ng] = acc[i][j][r] + bo[ng];
      }
}

// ---------- attention: KVBLK=64 staging, swizzled source ----------
__device__ __forceinline__ void stage_kv64(const unsigned short* __restrict__ kbase,
                                           const unsigned short* __restrict__ vbase,
                                           int k0, unsigned short* KsB,
                                           unsigned short* VsB, int tid) {
#pragma unroll
  for (int j = 0; j < 2; ++j) {
    const int c    = j * 256 + tid;   // 512 chunks of 16B: K[64][64]
    const int row  = c >> 3;
    const int colb = (c & 7) << 4;
    const int srcb = colb ^ ((row & 7) << 4);
    async16(kbase + (size_t)(k0 + row) * HD + (srcb >> 1), KsB + c * 8);
  }
#pragma unroll
  for (int j = 0; j < 2; ++j) {
    const int c    = j * 256 + tid;   // V[64 d][64 k]
    const int d    = c >> 3;
    const int colb = (c & 7) << 4;
    const int srcb = colb ^ ((d & 7) << 4);
    async16(vbase + (size_t)d * SEQ + k0 + (srcb >> 1), VsB + c * 8);
  }
}

// ---------- flash attention: single-Q block, double-buffered KVBLK=64 ----------
// grid (32 bh, 32 qbpos) x 256 threads. qb = 31-blockIdx.y, x-fastest =>
// globally longest-first (LPT); 1024 blocks at 4/CU give dynamic backfill.
// LDS = 2*8K (K) + 2*8K (V) + 8K (P) = 40960 B. Softmax in exp2 domain with
// Q pre-scaled; shuffle-free common path (defer-max); per-lane partial lsum.
__global__ __launch_bounds__(256)
void attn_k(const unsigned short* __restrict__ Q,
            const unsigned short* __restrict__ Kp,
            const unsigned short* __restrict__ Vt,
            const int* __restrict__ pm,
            unsigned short* __restrict__ O) {
  __shared__ __align__(16) unsigned short Ks[2][64 * 64];
  __shared__ __align__(16) unsigned short Vs[2][64 * 64];
  __shared__ __align__(16) unsigned short plds[4][16 * 64];

  const int tid  = threadIdx.x;
  const int lane = tid & 63;
  const int w    = tid >> 6;
  const int lc = lane & 15, lg = lane >> 4;
  const int qb = 31 - blockIdx.y;          // globally longest-first
  const int bh = blockIdx.x;
  const int b  = bh >> 4, h = bh & 15;

  const size_t base = (size_t)bh * SEQ * HD;
  const unsigned short* kbase = Kp + base;
  const unsigned short* vbase = Vt + (size_t)bh * HD * SEQ;
  const int* pmb = pm + b * SEQ;
  char* pb = (char*)&plds[w][0];
  const int swp = (lc & 7) << 4;

  const int qrow0 = qb * 64 + w * 16;
  const int qrow  = qrow0 + lc;

  short8 qa[2];
  {
    const unsigned short* qp = Q + base + (size_t)qrow * HD + lg * 8;
    qa[0] = *(const short8*)(qp);
    qa[1] = *(const short8*)(qp + 32);
  }

  f32x4 oacc[4] = {};
  float mrow = -1e30f, lsum = 0.f;

  const int nk = qb + 1;                   // 64-wide k-tiles to the diagonal

  stage_kv64(kbase, vbase, 0, Ks[0], Vs[0], tid);

  // per-wave padding-mask scan (overlaps DMA(0); no LDS flag)
  int ok = 1;
  for (int i = lane; i < SEQ / 4; i += 64) {
    int4 v = ((const int4*)pmb)[i];
    ok &= (v.x != 0) & (v.y != 0) & (v.z != 0) & (v.w != 0);
  }
  const bool allones = __all(ok);
  __syncthreads();   // DMA(0) drained

  for (int kt = 0; kt < nk; ++kt) {
    const int cur = kt & 1;
    const int k0 = kt * 64;
    if (kt + 1 < nk)
      stage_kv64(kbase, vbase, k0 + 64, Ks[cur ^ 1], Vs[cur ^ 1], tid);

    // ---- QK^T swapped: mfma(K, Q) -> lane holds S[q=qrow][k-slice];
    //      Q was pre-scaled by 0.125*log2(e) so z is already log2-domain ----
    f32x4 s[4];
    const char* kbuf = (const char*)Ks[cur];
    __builtin_amdgcn_s_setprio(1);
#pragma unroll
    for (int t = 0; t < 4; ++t) {
      const int row = t * 16 + lc;
      const int swk = (row & 7) << 4;
      const char* kr = kbuf + row * 128;
      short8 kb0 = *(const short8*)(kr + ((lg * 16) ^ swk));
      short8 kb1 = *(const short8*)(kr + ((lg * 16 + 64) ^ swk));
      f32x4 z = {};
      z = __builtin_amdgcn_mfma_f32_16x16x32_bf16(kb0, qa[0], z, 0, 0, 0);
      z = __builtin_amdgcn_mfma_f32_16x16x32_bf16(kb1, qa[1], z, 0, 0, 0);
      s[t] = z;
    }
    __builtin_amdgcn_s_setprio(0);

    // ---- masks: full work only if padding has zeros; else diagonal only ----
    if (!allones) {
#pragma unroll
      for (int t = 0; t < 4; ++t) {
        const int kr0 = k0 + t * 16;
        int4 pmv = *(const int4*)(pmb + kr0 + lg * 4);
#pragma unroll
        for (int r = 0; r < 4; ++r) {
          const int kidx = kr0 + lg * 4 + r;
          if (kidx > qrow || (&pmv.x)[r] == 0) s[t][r] = NEGV;
        }
      }
    } else if (kt == qb) {
#pragma unroll
      for (int t = 0; t < 4; ++t)
#pragma unroll
        for (int r = 0; r < 4; ++r) {
          const int kidx = k0 + t * 16 + lg * 4 + r;
          if (kidx > qrow) s[t][r] = NEGV;
        }
    }

    // ---- online softmax: shuffle-free common path (defer-max) ----
    float mx = -1e30f;
#pragma unroll
    for (int t = 0; t < 4; ++t)
      mx = fmaxf(mx, fmaxf(fmaxf(s[t][0], s[t][1]), fmaxf(s[t][2], s[t][3])));
    if (!__all(mx <= mrow + THR2)) {       // rare: true row max + rescale
      mx = fmaxf(mx, __shfl_xor(mx, 16, 64));
      mx = fmaxf(mx, __shfl_xor(mx, 32, 64));
      const float mnew = fmaxf(mrow, mx);
      const float sc = exp2f(mrow - mnew);
      lsum *= sc;
      mrow = mnew;
      const float s0 = __shfl(sc, lg * 4 + 0, 64);
      const float s1 = __shfl(sc, lg * 4 + 1, 64);
      const float s2 = __shfl(sc, lg * 4 + 2, 64);
      const float s3 = __shfl(sc, lg * 4 + 3, 64);
#pragma unroll
      for (int t = 0; t < 4; ++t) {
        oacc[t][0] *= s0; oacc[t][1] *= s1; oacc[t][2] *= s2; oacc[t][3] *= s3;
      }
    }
    // tree-form partial sums: 4 independent accumulators, short dep chain
    float ps[4];
#pragma unroll
    for (int t = 0; t < 4; ++t) {
      const float p0 = exp2f(s[t][0] - mrow);
      const float p1 = exp2f(s[t][1] - mrow);
      const float p2 = exp2f(s[t][2] - mrow);
      const float p3 = exp2f(s[t][3] - mrow);
      s[t][0] = p0; s[t][1] = p1; s[t][2] = p2; s[t][3] = p3;
      ps[t] = (p0 + p1) + (p2 + p3);
    }
    lsum += (ps[0] + ps[1]) + (ps[2] + ps[3]);   // per-lane partial

    // ---- P -> per-wave LDS (bf16, swizzled), wave-synchronous ----
#pragma unroll
    for (int t = 0; t < 4; ++t) {
      short4 pk;
      pk.x = (short)f2bf(s[t][0]); pk.y = (short)f2bf(s[t][1]);
      pk.z = (short)f2bf(s[t][2]); pk.w = (short)f2bf(s[t][3]);
      const int colb = (t * 16 + lg * 4) * 2;
      *(short4*)(pb + lc * 128 + (colb ^ swp)) = pk;
    }
    short8 pa[2];
#pragma unroll
    for (int ks = 0; ks < 2; ++ks)
      pa[ks] = *(const short8*)(pb + lc * 128 + (((ks * 32 + lg * 8) * 2) ^ swp));

    // ---- PV: O += P @ V, V fragments from swizzled LDS ----
    const char* vbuf = (const char*)Vs[cur];
    __builtin_amdgcn_s_setprio(1);
#pragma unroll
    for (int t = 0; t < 4; ++t) {
      const int d = t * 16 + lc;
      const int swv = (d & 7) << 4;
      const char* vr = vbuf + d * 128;
#pragma unroll
      for (int ks = 0; ks < 2; ++ks) {
        short8 vv = *(const short8*)(vr + ((ks * 64 + lg * 16) ^ swv));
        oacc[t] = __builtin_amdgcn_mfma_f32_16x16x32_bf16(pa[ks], vv, oacc[t], 0, 0, 0);
      }
    }
    __builtin_amdgcn_s_setprio(0);

    __syncthreads();   // drains stage(kt+1) DMA; all waves done with buf[cur]
  }

  // ---- epilogue: reduce partial lsum across the 4 row-copies, store ----
  lsum += __shfl_xor(lsum, 16, 64);
  lsum += __shfl_xor(lsum, 32, 64);
  const float l0 = __shfl(lsum, lg * 4 + 0, 64);
  const float l1 = __shfl(lsum, lg * 4 + 1, 64);
  const float l2 = __shfl(lsum, lg * 4 + 2, 64);
  const float l3 = __shfl(lsum, lg * 4 + 3, 64);
  const float i0 = 1.f / l0, i1 = 1.f / l1, i2 = 1.f / l2, i3 = 1.f / l3;
#pragma unroll
  for (int t = 0; t < 4; ++t) {
    const size_t o0 = ((size_t)(b * SEQ + qrow0 + lg * 4)) * DIM + h * HD + t * 16 + lc;
    O[o0]           = f2bf(oacc[t][0] * i0);
    O[o0 + DIM]     = f2bf(oacc[t][1] * i1);
    O[o0 + 2 * DIM] = f2bf(oacc[t][2] * i2);
    O[o0 + 3 * DIM] = f2bf(oacc[t][3] * i3);
  }
}

extern "C" void kernel_launch(void* const* d_in, const int* in_sizes, int n_in,
                              void* d_out, int out_size, void* d_ws, size_t ws_size,
                              hipStream_t stream) {
  const float* x  = (const float*)d_in[0];
  const int*   pm = (const int*)d_in[1];
  const float* Wq = (const float*)d_in[3];
  const float* bq = (const float*)d_in[4];
  const float* Wk = (const float*)d_in[5];
  const float* bk = (const float*)d_in[6];
  const float* Wv = (const float*)d_in[7];
  const float* bv = (const float*)d_in[8];
  const float* Wo = (const float*)d_in[9];
  const float* bo = (const float*)d_in[10];

  const size_t NX = (size_t)4096 * 1024;
  const size_t NW = (size_t)1024 * 1024;

  unsigned short* ws  = (unsigned short*)d_ws;
  unsigned short* xb  = ws;
  unsigned short* wqb = xb + NX;
  unsigned short* wkb = wqb + NW;
  unsigned short* wvb = wkb + NW;
  unsigned short* wob = wvb + NW;
  unsigned short* Qb  = wob + NW;
  unsigned short* Kb  = Qb + NX;
  unsigned short* Vtb = Kb + NX;
  unsigned short* Ob  = xb;   // alias: x no longer needed after QKV GEMM

  cast_all_k<<<dim3(1024, 5), dim3(256), 0, stream>>>(
      x, Wq, Wk, Wv, Wo, xb, wqb, wkb, wvb, wob,
      (int)(NX / 4), (int)(NW / 4));

  qkv_gemm_k<<<dim3(8, 32, 3), dim3(256), 0, stream>>>(xb, wqb, wkb, wvb,
                                                       bq, bk, bv, Qb, Kb, Vtb);

  attn_k<<<dim3(32, 32), dim3(256), 0, stream>>>(Qb, Kb, Vtb, pm, Ob);

  out_gemm_k<<<dim3(8, 32), dim3(256), 0, stream>>>(Ob, wob, bo, (float*)d_out);
}